// Round 9
// baseline (413.238 us; speedup 1.0000x reference)
//
#include <hip/hip_runtime.h>

typedef unsigned short u16;
typedef unsigned int u32;
typedef __attribute__((ext_vector_type(4))) float f32x4;
typedef __attribute__((ext_vector_type(8))) short s16x8;
typedef __attribute__((ext_vector_type(4))) unsigned int u32x4;

#define DEVI static __device__ __forceinline__

// B=2, S=2048, E=2048, H=16, D=128, MP=4, local=512; qkv cols: [q(512) v(512) k(512)] x4
// k-rope fused into QKV-GEMM epilogue; q-rope (+ (1/sqrt(128))*log2(e) scale) fused into
// attention prologue; softmax in exp2 domain.

#define ROPE_C (-13.287712379549449f / 32.0f)  // -log2(10000)/32
#define QSCALE 0.12751743f                     // log2(e)/sqrt(128)

DEVI u16 f2bf(float f) {
  u32 u = __float_as_uint(f);
  return (u16)((u + 0x7FFFu + ((u >> 16) & 1u)) >> 16);  // round-to-nearest-even
}
DEVI float bf2f(u16 h) { return __uint_as_float(((u32)h) << 16); }

DEVI void async_copy16(const u16* g, u16* l) {
  // dest = wave-uniform LDS base + lane*16 (gfx950 global_load_lds_dwordx4)
  __builtin_amdgcn_global_load_lds((__attribute__((address_space(1))) void*)g,
                                   (__attribute__((address_space(3))) void*)l, 16, 0, 0);
}

// fused fp32->bf16 cast of all three inputs
__global__ __launch_bounds__(256) void cast3_kernel(
    const float* __restrict__ s0, u16* __restrict__ d0, int n0,
    const float* __restrict__ s1, u16* __restrict__ d1, int n1,
    const float* __restrict__ s2, u16* __restrict__ d2, int n2) {
  int i = blockIdx.x * 256 + threadIdx.x;
  const float* s;
  u16* d;
  if (i < n0) {
    s = s0; d = d0;
  } else if (i < n0 + n1) {
    s = s1; d = d1; i -= n0;
  } else if (i < n0 + n1 + n2) {
    s = s2; d = d2; i -= n0 + n1;
  } else {
    return;
  }
  const float4 v = ((const float4*)s)[i];
  ushort4 o;
  o.x = f2bf(v.x); o.y = f2bf(v.y); o.z = f2bf(v.z); o.w = f2bf(v.w);
  ((ushort4*)d)[i] = o;
}

// C[m,n] = sum_k A[m,k]*B[n,k]; A,B row-major bf16, K contiguous (B^T GEMM).
// 128x128 tile, BK=32, 4 waves 2x2 of 64x64, 16x16x32 MFMA, 4x4 frags/wave.
// R4/R8 structure (best measured): A,B staged through 3-deep LDS via global_load_lds
// w16, XOR-swizzled, vmcnt(4) + raw s_barrier in steady state. Inline single-site
// epilogue with wave-uniform per-fragment part/head decode.
// EPI=0: C fp32 store. EPI=1: scatter qkv -> q[B,H,S,D], k(roped)[B,H,S,D], v^T[B,H,D,S].
template <int EPI>
__global__ __launch_bounds__(256, 3) void gemm_bt_kernel(
    const u16* __restrict__ A, const u16* __restrict__ Bm, int K, int N,
    float* __restrict__ C, u16* __restrict__ qo, u16* __restrict__ ko, u16* __restrict__ vo) {
  __shared__ __attribute__((aligned(16))) u16 As[3][128 * 32];  // 8KB each
  __shared__ __attribute__((aligned(16))) u16 Bs[3][128 * 32];  // 8KB each
  const int tid = threadIdx.x;
  const int w = tid >> 6, lane = tid & 63;
  const int quad = lane >> 4, l16 = lane & 15;
  const int wrow = (w >> 1) * 64, wcol = (w & 1) * 64;
  const long tileM = (long)blockIdx.y * 128;
  const long tileN = (long)blockIdx.x * 128;

  f32x4 acc[4][4];
#pragma unroll
  for (int i = 0; i < 4; ++i)
#pragma unroll
    for (int j = 0; j < 4; ++j) acc[i][j] = f32x4{0.f, 0.f, 0.f, 0.f};

  // staging: wave w covers tile rows [w*32, w*32+32) in two 16-row chunks.
  const u16* aptr[2];
  const u16* bptr[2];
  int ldso[2];
#pragma unroll
  for (int c = 0; c < 2; ++c) {
    const int r0 = (w * 2 + c) * 16;
    const int row = r0 + (lane >> 2);
    const int colsw = (((lane & 3) ^ ((row >> 1) & 3)) << 3);
    aptr[c] = A + (tileM + row) * (long)K + colsw;
    bptr[c] = Bm + (tileN + row) * (long)K + colsw;
    ldso[c] = r0 * 32;
  }

  auto stage = [&](int k0, int buf) {
#pragma unroll
    for (int c = 0; c < 2; ++c) {
      async_copy16(aptr[c] + k0, &As[buf][ldso[c]]);
      async_copy16(bptr[c] + k0, &Bs[buf][ldso[c]]);
    }
  };

  stage(0, 0);
  stage(32, 1);

  const int psw = (quad ^ ((l16 >> 1) & 3)) << 3;  // read-side swizzle (lane-constant)

  int bt = 0;
  for (int k0 = 0; k0 < K; k0 += 32) {
    if (k0 + 32 < K)
      __builtin_amdgcn_s_waitcnt(0x0f74);  // vmcnt(4): tile t landed, t+1 in flight
    else
      __builtin_amdgcn_s_waitcnt(0x0f70);  // last tile: vmcnt(0)
    __builtin_amdgcn_s_barrier();          // raw barrier: no compiler-forced drain
    if (k0 + 64 < K) stage(k0 + 64, bt == 0 ? 2 : bt - 1);

    s16x8 af[4], bfr[4];
#pragma unroll
    for (int i = 0; i < 4; ++i)
      af[i] = *(const s16x8*)(&As[bt][(wrow + i * 16 + l16) * 32 + psw]);
#pragma unroll
    for (int j = 0; j < 4; ++j)
      bfr[j] = *(const s16x8*)(&Bs[bt][(wcol + j * 16 + l16) * 32 + psw]);
#pragma unroll
    for (int i = 0; i < 4; ++i)
#pragma unroll
      for (int j = 0; j < 4; ++j)
        acc[i][j] = __builtin_amdgcn_mfma_f32_16x16x32_bf16(af[i], bfr[j], acc[i][j], 0, 0, 0);
    bt = bt == 2 ? 0 : bt + 1;
  }

  // ---- inline epilogue (single call site; acc stays in registers) ----
  const int b = (int)(tileM >> 11);  // 128-row tile never straddles batch
#pragma unroll
  for (int i = 0; i < 4; ++i) {
#pragma unroll
    for (int j = 0; j < 4; ++j) {
      const int rowb = (int)((tileM + wrow + i * 16 + quad * 4) & 2047);  // s of reg 0
      if (EPI == 0) {
#pragma unroll
        for (int r = 0; r < 4; ++r) {
          const long row = tileM + wrow + i * 16 + quad * 4 + r;
          C[row * N + tileN + wcol + j * 16 + l16] = acc[i][j][r];
        }
      } else {
        const long col0 = tileN + wcol + j * 16;  // wave-uniform base col of this frag
        const int mp = (int)(col0 / 1536);
        const int cc0 = (int)(col0 - (long)mp * 1536);
        const int part = cc0 >> 9;     // 0:q 1:v 2:k (uniform per frag)
        const int idx0 = cc0 & 511;
        const int head = mp * 4 + (idx0 >> 7);
        const int dim0 = idx0 & 127;
        const int dim = dim0 + l16;
        const long bh = (long)(b * 16 + head);
        if (part == 1) {
#pragma unroll
          for (int r = 0; r < 4; ++r)
            vo[(bh * 128 + dim) * 2048 + rowb + r] = f2bf(acc[i][j][r]);  // v^T
        } else {
          float y[4];
          if (part == 2 && dim0 < 64) {
            // k-rope: pair partner is adjacent lane (col parity == l16 parity)
            const int jj = dim >> 1;
            const float inv = exp2f((float)jj * ROPE_C);
#pragma unroll
            for (int r = 0; r < 4; ++r) {
              const float v = acc[i][j][r];
              const float pv = __shfl_xor(v, 1, 64);
              const float ang = (float)(rowb + r) * inv;
              const float sn = __sinf(ang), cs = __cosf(ang);
              y[r] = (l16 & 1) ? (v * cs + pv * sn) : (v * cs - pv * sn);
            }
          } else {
#pragma unroll
            for (int r = 0; r < 4; ++r) y[r] = acc[i][j][r];
          }
          u16* dst = (part == 0) ? qo : ko;
#pragma unroll
          for (int r = 0; r < 4; ++r)
            dst[(bh * 2048 + rowb + r) * 128 + dim] = f2bf(y[r]);
        }
      }
    }
  }
}

// Flash attention v5: swapped-operand + 128 q-rows/block (4 waves x 32 rows as two
// 16-row groups u=0,1). K/V fragment LDS reads are shared across both u-groups and
// barrier/staging phases per q-row halve vs v4. S^T = K*Q^T (keys in regs -> softmax
// = in-lane + 2 shfl, scalar m/l per lane per u); P -> PV B-operand via 8-shfl
// quad-exchange; PV = V^T*P -> out^T, ushort4 stores. Causal wave-skip: wave w
// computes tiles t <= 4qt+w (skip placed after barrier+stage; barriers stay uniform).
__global__ __launch_bounds__(256, 3) void attn_kernel(
    const u16* __restrict__ q, const u16* __restrict__ k,
    const u16* __restrict__ vT, u16* __restrict__ out) {
  __shared__ __attribute__((aligned(16))) u16 Ks[2][32 * 128];  // 8KB each
  __shared__ __attribute__((aligned(16))) u16 Vs[2][128 * 32];  // 8KB each
  const int tid = threadIdx.x;
  const int w = tid >> 6, lane = tid & 63;
  const int quad = lane >> 4, l16 = lane & 15;
  const int qt = 15 - (blockIdx.x >> 5);  // heavy tiles dispatched first
  const int bh = blockIdx.x & 31;
  const int qb0 = qt * 128 + w * 32;      // wave's first q-row

  const u16* qp = q + ((long)bh * 2048 + qb0) * 128;
  const u16* kp = k + (long)bh * 2048 * 128;
  const u16* vp = vT + (long)bh * 128 * 2048;

  // Q B-frags for both groups: Q[n=l16][kdim = c*32 + quad*8 + j], roped + scaled
  s16x8 qf[2][4];
#pragma unroll
  for (int u = 0; u < 2; ++u) {
    const float spos = (float)(qb0 + u * 16 + l16);
#pragma unroll
    for (int c = 0; c < 4; ++c) {
      const s16x8 raw = *(const s16x8*)(qp + (u * 16 + l16) * 128 + c * 32 + quad * 8);
      s16x8 ov;
      if (c < 2) {  // dims < 64: rotate pairs (in-lane: 2m, 2m+1)
#pragma unroll
        for (int m = 0; m < 4; ++m) {
          const int jj = c * 16 + quad * 4 + m;
          const float inv = exp2f((float)jj * ROPE_C);
          const float ang = spos * inv;
          const float sn = __sinf(ang), cs = __cosf(ang);
          const float x0 = bf2f((u16)raw[2 * m]), x1 = bf2f((u16)raw[2 * m + 1]);
          ov[2 * m] = (short)f2bf((x0 * cs - x1 * sn) * QSCALE);
          ov[2 * m + 1] = (short)f2bf((x1 * cs + x0 * sn) * QSCALE);
        }
      } else {      // dims >= 64: pass-through, scale only
#pragma unroll
        for (int e = 0; e < 8; ++e) ov[e] = (short)f2bf(bf2f((u16)raw[e]) * QSCALE);
      }
      qf[u][c] = ov;
    }
  }

  f32x4 acc[2][8];  // out^T per group: rows = dims dd*16+quad*4+r, col = q-row l16
#pragma unroll
  for (int u = 0; u < 2; ++u)
#pragma unroll
    for (int d = 0; d < 8; ++d) acc[u][d] = f32x4{0.f, 0.f, 0.f, 0.f};
  float mrun[2] = {-1e30f, -1e30f}, lrun[2] = {0.f, 0.f};

  // stage one 32-key tile: wave w stages keys [w*8,w*8+8) and dims [w*32,w*32+32)
  auto stage = [&](int k0, int buf) {
    const int ko = lane >> 4, cl = lane & 15;
#pragma unroll
    for (int i = 0; i < 2; ++i) {
      const int keyt = w * 8 + i * 4;
      const int key = keyt + ko;
      async_copy16(kp + (long)(k0 + key) * 128 + ((cl ^ (key & 15)) << 3),
                   &Ks[buf][keyt * 128]);
    }
    const int ld = lane >> 2, c4 = lane & 3;
#pragma unroll
    for (int i = 0; i < 2; ++i) {
      const int db = w * 32 + i * 16;
      const int d = db + ld;
      async_copy16(vp + (long)d * 2048 + k0 + ((c4 ^ ((d >> 1) & 3)) << 3),
                   &Vs[buf][db * 32]);
    }
  };

  stage(0, 0);

  const int nt = 4 * qt + 4;
  const int tmax = 4 * qt + w;  // last tile this wave computes (causal)
  for (int t = 0; t < nt; ++t) {
    const int k0 = t * 32;
    const u16* Ksc = Ks[t & 1];
    const u16* Vsc = Vs[t & 1];
    __builtin_amdgcn_s_waitcnt(0x0f70);  // vmcnt(0) only: my tile-t DMA done
    __syncthreads();                     // all waves' DMA done; prev buf free
    if (t + 1 < nt) stage(k0 + 32, (t + 1) & 1);
    if (t > tmax) continue;              // wave-uniform compute skip (after barrier+stage)

    // S^T = K*Q^T: sc[u][g] rows = keys k0+g*16+quad*4+r, col = q-row of group u
    f32x4 sc[2][2];
#pragma unroll
    for (int u = 0; u < 2; ++u)
#pragma unroll
      for (int g = 0; g < 2; ++g) sc[u][g] = f32x4{0.f, 0.f, 0.f, 0.f};
#pragma unroll
    for (int g = 0; g < 2; ++g)
#pragma unroll
      for (int c = 0; c < 4; ++c) {
        const s16x8 kf = *(const s16x8*)(
            &Ksc[(g * 16 + l16) * 128 + ((((c << 2) + quad) ^ l16) << 3)]);
        sc[0][g] = __builtin_amdgcn_mfma_f32_16x16x32_bf16(kf, qf[0][c], sc[0][g], 0, 0, 0);
        sc[1][g] = __builtin_amdgcn_mfma_f32_16x16x32_bf16(kf, qf[1][c], sc[1][g], 0, 0, 0);
      }

    s16x8 pf[2];
#pragma unroll
    for (int u = 0; u < 2; ++u) {
      if (k0 + 31 > qb0 + u * 16) {  // tile crosses diagonal for group u (uniform)
        const int qrow = qb0 + u * 16 + l16;
#pragma unroll
        for (int g = 0; g < 2; ++g) {
          const int keyb = k0 + g * 16 + quad * 4;
#pragma unroll
          for (int r = 0; r < 4; ++r)
            if (keyb + r > qrow) sc[u][g][r] = -1e30f;
        }
      }
      // online softmax (exp2 domain): keys in regs + across quads
      float mx = fmaxf(fmaxf(fmaxf(sc[u][0][0], sc[u][0][1]), fmaxf(sc[u][0][2], sc[u][0][3])),
                       fmaxf(fmaxf(sc[u][1][0], sc[u][1][1]), fmaxf(sc[u][1][2], sc[u][1][3])));
      mx = fmaxf(mx, __shfl_xor(mx, 16, 64));
      mx = fmaxf(mx, __shfl_xor(mx, 32, 64));
      const float mnew = fmaxf(mrun[u], mx);
      const float alpha = exp2f(mrun[u] - mnew);
      mrun[u] = mnew;
      float p[2][4];
      float sm = 0.f;
#pragma unroll
      for (int g = 0; g < 2; ++g)
#pragma unroll
        for (int r = 0; r < 4; ++r) { p[g][r] = exp2f(sc[u][g][r] - mnew); sm += p[g][r]; }
      sm += __shfl_xor(sm, 16, 64);
      sm += __shfl_xor(sm, 32, 64);
      lrun[u] = lrun[u] * alpha + sm;
#pragma unroll
      for (int d = 0; d < 8; ++d)
#pragma unroll
        for (int r = 0; r < 4; ++r) acc[u][d][r] *= alpha;

      // quad-exchange P (S^T C-layout) -> PV B-frag P[n=qrow l16][k=key quad*8+j]
      u32 pk[2][2];
#pragma unroll
      for (int g = 0; g < 2; ++g) {
        pk[g][0] = (u32)f2bf(p[g][0]) | ((u32)f2bf(p[g][1]) << 16);
        pk[g][1] = (u32)f2bf(p[g][2]) | ((u32)f2bf(p[g][3]) << 16);
      }
      const int la = ((quad & 1) << 5) + l16;
      const int lb = la + 16;
      const u32 a0 = (u32)__shfl((int)pk[0][0], la, 64);
      const u32 a1 = (u32)__shfl((int)pk[0][1], la, 64);
      const u32 a2 = (u32)__shfl((int)pk[0][0], lb, 64);
      const u32 a3 = (u32)__shfl((int)pk[0][1], lb, 64);
      const u32 b0 = (u32)__shfl((int)pk[1][0], la, 64);
      const u32 b1 = (u32)__shfl((int)pk[1][1], la, 64);
      const u32 b2 = (u32)__shfl((int)pk[1][0], lb, 64);
      const u32 b3 = (u32)__shfl((int)pk[1][1], lb, 64);
      const bool hi = quad >= 2;
      const u32x4 pw = {hi ? b0 : a0, hi ? b1 : a1, hi ? b2 : a2, hi ? b3 : a3};
      pf[u] = __builtin_bit_cast(s16x8, pw);
    }

    // PV: out^T += V^T * P (V-frags shared across both u-groups)
#pragma unroll
    for (int dd = 0; dd < 8; ++dd) {
      const s16x8 vf = *(const s16x8*)(
          &Vsc[(dd * 16 + l16) * 32 + ((quad ^ ((l16 >> 1) & 3)) << 3)]);
      acc[0][dd] = __builtin_amdgcn_mfma_f32_16x16x32_bf16(vf, pf[0], acc[0][dd], 0, 0, 0);
      acc[1][dd] = __builtin_amdgcn_mfma_f32_16x16x32_bf16(vf, pf[1], acc[1][dd], 0, 0, 0);
    }
  }

  // epilogue: lane l16 owns q-row qb0+u*16+l16; dims dd*16+quad*4+r -> ushort4 stores
  const int b = bh >> 4, h = bh & 15;
#pragma unroll
  for (int u = 0; u < 2; ++u) {
    u16* op = out + ((long)b * 2048 + qb0 + u * 16 + l16) * 2048 + h * 128;
    const float inv_l = 1.0f / lrun[u];
#pragma unroll
    for (int dd = 0; dd < 8; ++dd) {
      ushort4 o4;
      o4.x = f2bf(acc[u][dd][0] * inv_l);
      o4.y = f2bf(acc[u][dd][1] * inv_l);
      o4.z = f2bf(acc[u][dd][2] * inv_l);
      o4.w = f2bf(acc[u][dd][3] * inv_l);
      *(ushort4*)(op + dd * 16 + quad * 4) = o4;
    }
  }
}

extern "C" void kernel_launch(void* const* d_in, const int* in_sizes, int n_in,
                              void* d_out, int out_size, void* d_ws, size_t ws_size,
                              hipStream_t stream) {
  const float* hidden = (const float*)d_in[0];  // [2,2048,2048]
  const float* w_qkv = (const float*)d_in[1];   // [6144,2048]
  const float* w_out = (const float*)d_in[2];   // [2048,2048]
  float* out = (float*)d_out;                   // [2,2048,2048] fp32
  char* ws = (char*)d_ws;

  // workspace layout (112 MB total, all 16B aligned)
  u16* hid_b  = (u16*)(ws + (size_t)0);          // hidden bf16
  u16* wqkv_b = (u16*)(ws + (size_t)16777216);   // w_qkv bf16
  u16* wout_b = (u16*)(ws + (size_t)41943040);   // w_out bf16
  u16* qb     = (u16*)(ws + (size_t)50331648);   // q (unroped) [B,H,S,D]
  u16* kb     = (u16*)(ws + (size_t)67108864);   // k (roped)   [B,H,S,D]
  u16* vb     = (u16*)(ws + (size_t)83886080);   // v^T [B,H,D,S]
  u16* ao     = (u16*)(ws + (size_t)100663296);  // attn out [B,S,E]

  cast3_kernel<<<24576, 256, 0, stream>>>(hidden, hid_b, 2097152,
                                          w_qkv, wqkv_b, 3145728,
                                          w_out, wout_b, 1048576);

  // qkv projection, fused split/transpose/k-rope epilogue
  gemm_bt_kernel<1><<<dim3(48, 32), 256, 0, stream>>>(hid_b, wqkv_b, 2048, 6144,
                                                      nullptr, qb, kb, vb);
  // causal flash attention (q-rope + scale in prologue), 128 q-rows/block
  attn_kernel<<<512, 256, 0, stream>>>(qb, kb, vb, ao);
  // output projection -> fp32
  gemm_bt_kernel<0><<<dim3(16, 32), 256, 0, stream>>>(ao, wout_b, 2048, 2048,
                                                      out, nullptr, nullptr, nullptr);
}